// Round 5
// baseline (526.598 us; speedup 1.0000x reference)
//
#include <hip/hip_runtime.h>
#include <hip/hip_bf16.h>
#include <cstdint>
#include <cstddef>

// Problem constants
#define NTOK 49
#define DIM 384
#define HEADS 12
#define HD 32
#define BATCH 2048

typedef unsigned short u16;
typedef __bf16 bf16x8 __attribute__((ext_vector_type(8)));
typedef unsigned short u16x8 __attribute__((ext_vector_type(8)));
typedef float f32x4 __attribute__((ext_vector_type(4)));

__device__ __forceinline__ u16 f2b(float f) {
  union { float f; unsigned u; } v; v.f = f;
  unsigned r = v.u + 0x7fffu + ((v.u >> 16) & 1u);   // RNE bf16
  return (u16)(r >> 16);
}

__device__ __forceinline__ bf16x8 ld_bf8(const u16* p) {
  u16x8 u = *(const u16x8*)p;
  return __builtin_bit_cast(bf16x8, u);
}

#define MFMA16(a, b, cacc) __builtin_amdgcn_mfma_f32_16x16x32_bf16(a, b, cacc, 0, 0, 0)

// ---------------- prep: weight casts + fused bias+mask table ----------------
// blocks [0,432): cast qkv_w (110,592 float4 quads)
// blocks [432,576): cast proj_w (36,864 quads)
// blocks [576,12864): rpbm table (3,145,728 entries = 12288 blocks)
__global__ __launch_bounds__(256) void k_prep(const float* __restrict__ qkv_w,
                                              u16* __restrict__ wqkvb,
                                              const float* __restrict__ proj_w,
                                              u16* __restrict__ wprojb,
                                              const float* __restrict__ bias_table,
                                              const float* __restrict__ mask,
                                              const int* __restrict__ rel_idx,
                                              float* __restrict__ rpbm) {
  int blk = blockIdx.x;
  if (blk < 576) {
    const float* in;
    u16* out;
    int i;
    if (blk < 432) { in = qkv_w; out = wqkvb; i = blk * 256 + threadIdx.x; }
    else           { in = proj_w; out = wprojb; i = (blk - 432) * 256 + threadIdx.x; }
    float4 v = ((const float4*)in)[i];
    ushort4 o;
    o.x = f2b(v.x); o.y = f2b(v.y); o.z = f2b(v.z); o.w = f2b(v.w);
    ((ushort4*)out)[i] = o;
  } else {
    int idx = (blk - 576) * 256 + threadIdx.x;   // 12*64*4096 = 3,145,728 entries
    int r  = idx & 3;
    int l  = (idx >> 2) & 63;
    int ni = (idx >> 8) & 3;
    int mi = (idx >> 10) & 3;
    int w  = (idx >> 12) & 63;
    int h  = idx >> 18;
    int row = mi * 16 + (l >> 4) * 4 + r;
    int col = ni * 16 + (l & 15);
    float v = -1e30f;
    if (row < NTOK && col < NTOK)
      v = bias_table[rel_idx[row * NTOK + col] * HEADS + h] +
          mask[(w * NTOK + row) * NTOK + col];
    rpbm[idx] = v;
  }
}

// ---------------- fully fused: qkv GEMM + window attention + proj ----------
// One block per window b. 4 waves; wave owns 3 heads end-to-end, then the
// 4 waves split the proj GEMM by output columns.
//
// LDS map (byte offsets), total 161,792 B (<= 160 KiB):
//   xs  @ 0      : x[b] bf16, 64 rows x 784 B (384 elems + 16B pad; rows 49..63 zero)
//   O   @ 50176  : attention out bf16, 64 rows x 784 B
//   wv  @ 100352 + wid*15360 : per-wave scratch:
//        q  @ +0     : [64 tok][32 d], stride 80 B  (bank-spread, 16B-aligned)
//        k  @ +5120  : [64 tok][32 d], stride 80 B
//        vT @ +10240 : [32 d][64 tok], stride 144 B
//        P  @ +0     : [64 tok][64 j], stride 144 B (overlays q+k after S)
__global__ __launch_bounds__(256, 1) void k_fused(const float* __restrict__ x,
                                                  const u16* __restrict__ wqkv,
                                                  const float* __restrict__ qkv_b,
                                                  const u16* __restrict__ wproj,
                                                  const float* __restrict__ proj_b,
                                                  const float* __restrict__ rpbm,
                                                  float* __restrict__ out) {
  __shared__ __attribute__((aligned(16))) char lds[161792];
  const int b = blockIdx.x;
  const int w = b & 63;
  const int tid = threadIdx.x;
  const int lane = tid & 63, wid = tid >> 6;
  const int c = lane & 15, g = lane >> 4;
  char* xs = lds;
  char* Ob = lds + 50176;
  char* wv = lds + 100352 + wid * 15360;

  // ---- load x[b] (f32) -> xs bf16; zero pad rows 49..63 ----
  {
    const float4* xp = (const float4*)(x + (size_t)b * (NTOK * DIM));
    for (int i = tid; i < 4704; i += 256) {         // 49*96 float4
      float4 v = xp[i];
      int row = i / 96, col4 = i - row * 96;
      ushort4 o;
      o.x = f2b(v.x); o.y = f2b(v.y); o.z = f2b(v.z); o.w = f2b(v.w);
      *(ushort4*)(xs + row * 784 + col4 * 8) = o;
    }
    uint4 z = {0, 0, 0, 0};
    for (int t = tid; t < 735; t += 256)            // 15 rows * 784B / 16
      *(uint4*)(xs + 38416 + t * 16) = z;
  }
  __syncthreads();

  const float scale = 0.17677669529663687f;         // 32^-0.5

#define LOAD_AB(af, bf, kt, ABASE, ASTRIDE, BPTR)                               \
  _Pragma("unroll") for (int mi = 0; mi < 4; ++mi)                              \
      af[mi] = ld_bf8((const u16*)((ABASE) + (mi * 16 + c) * (ASTRIDE)) +       \
                      (kt) * 32 + g * 8);                                       \
  _Pragma("unroll") for (int nj = 0; nj < 6; ++nj)                              \
      bf[nj] = ld_bf8(BPTR[nj] + (kt) * 32);

#define MFMA_46(af, bf, ACC)                                                    \
  _Pragma("unroll") for (int mi = 0; mi < 4; ++mi)                              \
  _Pragma("unroll") for (int nj = 0; nj < 6; ++nj)                              \
      ACC[mi][nj] = MFMA16(af[mi], bf[nj], ACC[mi][nj]);

  // ================= per-wave: 3 heads end-to-end =================
  for (int hh = 0; hh < 3; ++hh) {
    const int h = wid * 3 + hh;

    // ---- qkv GEMM for head h: C[64 tok][96] = xs @ Wqkv_h^T ----
    int ncol[6];
    ncol[0] = h * 32;        ncol[1] = h * 32 + 16;
    ncol[2] = 384 + h * 32;  ncol[3] = 384 + h * 32 + 16;
    ncol[4] = 768 + h * 32;  ncol[5] = 768 + h * 32 + 16;
    const u16* bp[6];
#pragma unroll
    for (int nj = 0; nj < 6; ++nj)
      bp[nj] = wqkv + (size_t)(ncol[nj] + c) * 384 + g * 8;

    f32x4 acc[4][6] = {};
    {
      bf16x8 afA[4], bfA[6], afB[4], bfB[6];
      LOAD_AB(afA, bfA, 0, xs, 784, bp);
#pragma unroll
      for (int kt = 0; kt < 12; kt += 2) {
        if (kt + 1 < 12) { LOAD_AB(afB, bfB, kt + 1, xs, 784, bp); }
        MFMA_46(afA, bfA, acc);
        if (kt + 2 < 12) { LOAD_AB(afA, bfA, kt + 2, xs, 784, bp); }
        MFMA_46(afB, bfB, acc);
      }
    }

    // WAR guard: previous head's P/vT reads must complete before overwrite
    asm volatile("s_waitcnt lgkmcnt(0)" ::: "memory");
    __builtin_amdgcn_sched_barrier(0);

    // ---- bias (+scale for q), scatter to q / k / vT ----
#pragma unroll
    for (int nj = 0; nj < 6; ++nj) {
      float bv = qkv_b[ncol[nj] + c];
      int d = (nj & 1) * 16 + c;
#pragma unroll
      for (int mi = 0; mi < 4; ++mi) {
#pragma unroll
        for (int r = 0; r < 4; ++r) {
          int tok = mi * 16 + g * 4 + r;
          float v = acc[mi][nj][r] + bv;
          if (nj < 2)
            *(u16*)(wv + tok * 80 + d * 2) = f2b(v * scale);        // q
          else if (nj < 4)
            *(u16*)(wv + 5120 + tok * 80 + d * 2) = f2b(v);         // k
          else
            *(u16*)(wv + 10240 + d * 144 + tok * 2) = f2b(v);       // vT
        }
      }
    }
    asm volatile("s_waitcnt lgkmcnt(0)" ::: "memory");
    __builtin_amdgcn_sched_barrier(0);

    // ---- S = q @ k^T (K = 32, one MFMA step) ----
    f32x4 s[4][4];
    {
      bf16x8 qf[4], kf[4];
#pragma unroll
      for (int i = 0; i < 4; ++i) {
        qf[i] = ld_bf8((const u16*)(wv + (i * 16 + c) * 80) + g * 8);
        kf[i] = ld_bf8((const u16*)(wv + 5120 + (i * 16 + c) * 80) + g * 8);
      }
      f32x4 zf = {0.f, 0.f, 0.f, 0.f};
#pragma unroll
      for (int mi = 0; mi < 4; ++mi)
#pragma unroll
        for (int nj = 0; nj < 4; ++nj)
          s[mi][nj] = MFMA16(qf[mi], kf[nj], zf);
    }

    // ---- add pre-swizzled bias+mask ----
    const f32x4* rp = (const f32x4*)(rpbm + ((size_t)(h * 64 + w)) * 4096);
#pragma unroll
    for (int mi = 0; mi < 4; ++mi)
#pragma unroll
      for (int nj = 0; nj < 4; ++nj) {
        f32x4 rv = rp[(mi * 4 + nj) * 64 + lane];
#pragma unroll
        for (int r = 0; r < 4; ++r) s[mi][nj][r] += rv[r];
      }

    // ---- row softmax (row's 64 cols live across the 16-lane c-group) ----
#pragma unroll
    for (int mi = 0; mi < 4; ++mi)
#pragma unroll
      for (int r = 0; r < 4; ++r) {
        float mx = fmaxf(fmaxf(s[mi][0][r], s[mi][1][r]),
                         fmaxf(s[mi][2][r], s[mi][3][r]));
        mx = fmaxf(mx, __shfl_xor(mx, 1));
        mx = fmaxf(mx, __shfl_xor(mx, 2));
        mx = fmaxf(mx, __shfl_xor(mx, 4));
        mx = fmaxf(mx, __shfl_xor(mx, 8));
        float sum = 0.f;
#pragma unroll
        for (int nj = 0; nj < 4; ++nj) {
          float p = __expf(s[mi][nj][r] - mx);
          s[mi][nj][r] = p;
          sum += p;
        }
        sum += __shfl_xor(sum, 1);
        sum += __shfl_xor(sum, 2);
        sum += __shfl_xor(sum, 4);
        sum += __shfl_xor(sum, 8);
        float inv = __builtin_amdgcn_rcpf(sum);
#pragma unroll
        for (int nj = 0; nj < 4; ++nj) s[mi][nj][r] *= inv;
      }

    // ---- P -> LDS bf16 (overlays q,k; stride 144) ----
#pragma unroll
    for (int mi = 0; mi < 4; ++mi)
#pragma unroll
      for (int nj = 0; nj < 4; ++nj) {
        int col = nj * 16 + c;
#pragma unroll
        for (int r = 0; r < 4; ++r) {
          int tok = mi * 16 + g * 4 + r;
          *(u16*)(wv + tok * 144 + col * 2) = f2b(s[mi][nj][r]);
        }
      }
    asm volatile("s_waitcnt lgkmcnt(0)" ::: "memory");
    __builtin_amdgcn_sched_barrier(0);

    // ---- O_h = P @ V (K = 64, two MFMA steps) ----
    f32x4 o[4][2] = {};
#pragma unroll
    for (int ks = 0; ks < 2; ++ks) {
      bf16x8 vf[2];
#pragma unroll
      for (int n2 = 0; n2 < 2; ++n2)
        vf[n2] = ld_bf8((const u16*)(wv + 10240 + (n2 * 16 + c) * 144) +
                        ks * 32 + g * 8);
#pragma unroll
      for (int mi = 0; mi < 4; ++mi) {
        bf16x8 pa = ld_bf8((const u16*)(wv + (mi * 16 + c) * 144) + ks * 32 + g * 8);
#pragma unroll
        for (int n2 = 0; n2 < 2; ++n2)
          o[mi][n2] = MFMA16(pa, vf[n2], o[mi][n2]);
      }
    }

    // ---- O_h -> shared O buffer (cols h*32..h*32+31) ----
#pragma unroll
    for (int mi = 0; mi < 4; ++mi)
#pragma unroll
      for (int n2 = 0; n2 < 2; ++n2) {
        int ocol = h * 32 + n2 * 16 + c;
#pragma unroll
        for (int r = 0; r < 4; ++r) {
          int tok = mi * 16 + g * 4 + r;
          *(u16*)(Ob + tok * 784 + ocol * 2) = f2b(o[mi][n2][r]);
        }
      }
  }

  __syncthreads();   // all heads' O visible to all waves

  // ================= proj: out[64,384] = O @ Wproj^T + b =================
  {
    const int oc0 = wid * 96;
    const u16* pp[6];
#pragma unroll
    for (int nj = 0; nj < 6; ++nj)
      pp[nj] = wproj + (size_t)(oc0 + nj * 16 + c) * 384 + g * 8;

    f32x4 ap[4][6] = {};
    {
      bf16x8 afA[4], bfA[6], afB[4], bfB[6];
      LOAD_AB(afA, bfA, 0, Ob, 784, pp);
#pragma unroll
      for (int kt = 0; kt < 12; kt += 2) {
        if (kt + 1 < 12) { LOAD_AB(afB, bfB, kt + 1, Ob, 784, pp); }
        MFMA_46(afA, bfA, ap);
        if (kt + 2 < 12) { LOAD_AB(afA, bfA, kt + 2, Ob, 784, pp); }
        MFMA_46(afB, bfB, ap);
      }
    }

#pragma unroll
    for (int nj = 0; nj < 6; ++nj) {
      float bv = proj_b[oc0 + nj * 16 + c];
#pragma unroll
      for (int mi = 0; mi < 4; ++mi) {
#pragma unroll
        for (int r = 0; r < 4; ++r) {
          int tok = mi * 16 + g * 4 + r;
          if (tok < NTOK)
            out[((size_t)b * NTOK + tok) * 384 + oc0 + nj * 16 + c] =
                ap[mi][nj][r] + bv;
        }
      }
    }
  }
#undef LOAD_AB
#undef MFMA_46
}

// ---------------------------------------------------------------------------
extern "C" void kernel_launch(void* const* d_in, const int* in_sizes, int n_in,
                              void* d_out, int out_size, void* d_ws, size_t ws_size,
                              hipStream_t stream) {
  const float* x       = (const float*)d_in[0];
  const float* qkv_w   = (const float*)d_in[1];
  const float* qkv_b   = (const float*)d_in[2];
  const float* proj_w  = (const float*)d_in[3];
  const float* proj_b  = (const float*)d_in[4];
  const float* bias_tb = (const float*)d_in[5];
  const float* mask    = (const float*)d_in[6];
  const int*   rel_idx = (const int*)d_in[7];
  float* out = (float*)d_out;

  char* ws = (char*)d_ws;
  u16*   wqkvb  = (u16*)(ws + 0);             //    884,736 B  qkv_w bf16
  u16*   wprojb = (u16*)(ws + 884736);        //    294,912 B  proj_w bf16
  float* rpbm   = (float*)(ws + 1179648);     // 12,582,912 B  bias+mask table
  // total ws use: 13,762,560 B

  // 1) prep: weight casts + fused bias+mask table
  k_prep<<<12864, 256, 0, stream>>>(qkv_w, wqkvb, proj_w, wprojb,
                                    bias_tb, mask, rel_idx, rpbm);

  // 2) fully fused qkv + attention + proj, one block per window
  k_fused<<<BATCH, 256, 0, stream>>>(x, wqkvb, qkv_b, wprojb, proj_b, rpbm, out);

  (void)in_sizes; (void)n_in; (void)out_size; (void)ws_size;
}